// Round 1
// baseline (920.905 us; speedup 1.0000x reference)
//
#include <hip/hip_runtime.h>
#include <math.h>

#define C 128

// ---------------------------------------------------------------- utilities
__device__ inline unsigned long long shfl_down_u64(unsigned long long x, int o) {
    unsigned lo = (unsigned)x, hi = (unsigned)(x >> 32);
    lo = __shfl_down(lo, o);
    hi = __shfl_down(hi, o);
    return ((unsigned long long)hi << 32) | lo;
}

// ---------------------------------------------------------------- init: deg=1 (self loop), cnt=0
__global__ void k_init(float* __restrict__ deg, int* __restrict__ cnt, int N) {
    int i = blockIdx.x * blockDim.x + threadIdx.x;
    if (i < N) { deg[i] = 1.0f; cnt[i] = 0; }
}

// ---------------------------------------------------------------- scores: s[i] = X[i,:] . p  (unnormalized)
__global__ void k_scores(const float* __restrict__ X, const float* __restrict__ p,
                         float* __restrict__ scores, int N) {
    int wid  = (int)((blockIdx.x * (size_t)blockDim.x + threadIdx.x) >> 6);
    int lane = threadIdx.x & 63;
    if (wid >= N) return;
    const float* xr = X + (size_t)wid * C;
    float a = xr[lane] * p[lane] + xr[lane + 64] * p[lane + 64];
    #pragma unroll
    for (int o = 32; o; o >>= 1) a += __shfl_down(a, o);
    if (lane == 0) scores[wid] = a;
}

// ---------------------------------------------------------------- degree + count histogram over edges
__global__ void k_deghist(const int* __restrict__ ei, const float* __restrict__ ew,
                          float* __restrict__ deg, int* __restrict__ cnt, int E) {
    int e = blockIdx.x * blockDim.x + threadIdx.x;
    if (e < E) {
        int d = ei[E + e];
        atomicAdd(&deg[d], ew[e]);
        atomicAdd(&cnt[d], 1);
    }
}

// ---------------------------------------------------------------- exact top-128 (value desc, idx asc tie-break)
#define TKT 512
#define TKS 98   // 512*98 = 50176 >= 50000
__global__ __launch_bounds__(TKT) void k_topk(const float* __restrict__ scores,
                                              const float* __restrict__ p,
                                              int* __restrict__ tidx, float* __restrict__ gate,
                                              int N) {
    __shared__ unsigned long long wmax[TKT / 64];
    __shared__ float pred[TKT / 64];
    __shared__ unsigned long long s_win;
    __shared__ float s_pn;
    int t = threadIdx.x;

    // ||p||
    float pv = 0.f;
    if (t < C) { float x = p[t]; pv = x * x; }
    #pragma unroll
    for (int o = 32; o; o >>= 1) pv += __shfl_down(pv, o);
    if ((t & 63) == 0) pred[t >> 6] = pv;
    __syncthreads();
    if (t == 0) {
        float s = 0.f;
        for (int i = 0; i < TKT / 64; i++) s += pred[i];
        s_pn = sqrtf(s);
    }

    // load packed keys into registers; key = ord(score)<<32 | ~idx  (0 = invalid)
    unsigned long long key[TKS];
    unsigned long long best = 0;
    #pragma unroll
    for (int s = 0; s < TKS; s++) {
        int i = t + s * TKT;
        unsigned long long k = 0;
        if (i < N) {
            unsigned u = __float_as_uint(scores[i]);
            u ^= (u & 0x80000000u) ? 0xFFFFFFFFu : 0x80000000u;
            k = ((unsigned long long)u << 32) | (unsigned)(~(unsigned)i);
        }
        key[s] = k;
        if (k > best) best = k;
    }
    __syncthreads();

    for (int it = 0; it < C; it++) {
        unsigned long long m = best;
        #pragma unroll
        for (int o = 32; o; o >>= 1) {
            unsigned long long v = shfl_down_u64(m, o);
            if (v > m) m = v;
        }
        if ((t & 63) == 0) wmax[t >> 6] = m;
        __syncthreads();
        if (t == 0) {
            unsigned long long g = 0;
            for (int i = 0; i < TKT / 64; i++) if (wmax[i] > g) g = wmax[i];
            s_win = g;
            unsigned u = (unsigned)(g >> 32);
            u ^= (u & 0x80000000u) ? 0x80000000u : 0xFFFFFFFFu;
            tidx[it] = (int)(~(unsigned)(g & 0xFFFFFFFFull));
            gate[it] = tanhf(__uint_as_float(u) / s_pn);
        }
        __syncthreads();
        unsigned long long g = s_win;
        if (best == g) {   // this thread owned the winner: invalidate + rescan
            best = 0;
            #pragma unroll
            for (int s = 0; s < TKS; s++) {
                if (key[s] == g) key[s] = 0;
                if (key[s] > best) best = key[s];
            }
        }
        __syncthreads();
    }
}

// ---------------------------------------------------------------- X_tilde = X[idx] * gate
__global__ void k_xtilde(const float* __restrict__ X, const int* __restrict__ tidx,
                         const float* __restrict__ gate, float* __restrict__ xtl) {
    int gid = blockIdx.x * blockDim.x + threadIdx.x;   // 16384 threads
    int i = gid >> 7, k = gid & 127;
    xtl[gid] = X[(size_t)tidx[i] * C + k] * gate[i];
}

// ---------------------------------------------------------------- scan: offsets, cursor, dinv
#define SCT 1024
#define SCC 49   // 1024*49 = 50176 >= 50000
__global__ __launch_bounds__(SCT) void k_scan(const int* __restrict__ cnt, const float* __restrict__ deg,
                                              int* __restrict__ offs, int* __restrict__ cursor,
                                              float* __restrict__ dinv, int N, int E) {
    __shared__ int sc[SCT];
    int t = threadIdx.x;
    int start = t * SCC;
    int sum = 0;
    for (int s = 0; s < SCC; s++) {
        int i = start + s;
        if (i < N) sum += cnt[i];
    }
    sc[t] = sum;
    __syncthreads();
    for (int off = 1; off < SCT; off <<= 1) {
        int v = (t >= off) ? sc[t - off] : 0;
        __syncthreads();
        sc[t] += v;
        __syncthreads();
    }
    int run = sc[t] - sum;   // exclusive prefix of chunk
    for (int s = 0; s < SCC; s++) {
        int i = start + s;
        if (i < N) {
            offs[i] = run;
            cursor[i] = run;
            run += cnt[i];
            dinv[i] = rsqrtf(deg[i]);   // deg >= 1 always (self loop)
        }
    }
    if (t == 0) offs[N] = E;
}

// ---------------------------------------------------------------- GRU step -> W_new^T  (layout [k][c])
__global__ __launch_bounds__(256) void k_gru(const float* __restrict__ xtl, const float* __restrict__ Wc,
                                             const float* __restrict__ W_ih, const float* __restrict__ W_hh,
                                             const float* __restrict__ b_ih, const float* __restrict__ b_hh,
                                             float* __restrict__ wnewT) {
    int t = threadIdx.x;
    int i = t & 127;
    int j = blockIdx.x * 2 + (t >> 7);
    const float4* xr   = (const float4*)(xtl + (size_t)i * C);
    const float4* hr   = (const float4*)(Wc + (size_t)i * C);
    const float4* wri  = (const float4*)(W_ih + (size_t)j * C);
    const float4* wzi  = (const float4*)(W_ih + (size_t)(C + j) * C);
    const float4* wni  = (const float4*)(W_ih + (size_t)(2 * C + j) * C);
    const float4* wrh  = (const float4*)(W_hh + (size_t)j * C);
    const float4* wzh  = (const float4*)(W_hh + (size_t)(C + j) * C);
    const float4* wnh  = (const float4*)(W_hh + (size_t)(2 * C + j) * C);
    float gir = 0, giz = 0, gin = 0, ghr = 0, ghz = 0, ghn = 0;
    #pragma unroll 8
    for (int k4 = 0; k4 < C / 4; k4++) {
        float4 x = xr[k4], h = hr[k4], a;
        a = wri[k4]; gir += x.x * a.x + x.y * a.y + x.z * a.z + x.w * a.w;
        a = wzi[k4]; giz += x.x * a.x + x.y * a.y + x.z * a.z + x.w * a.w;
        a = wni[k4]; gin += x.x * a.x + x.y * a.y + x.z * a.z + x.w * a.w;
        a = wrh[k4]; ghr += h.x * a.x + h.y * a.y + h.z * a.z + h.w * a.w;
        a = wzh[k4]; ghz += h.x * a.x + h.y * a.y + h.z * a.z + h.w * a.w;
        a = wnh[k4]; ghn += h.x * a.x + h.y * a.y + h.z * a.z + h.w * a.w;
    }
    gir += b_ih[j];         ghr += b_hh[j];
    giz += b_ih[C + j];     ghz += b_hh[C + j];
    gin += b_ih[2 * C + j]; ghn += b_hh[2 * C + j];
    float r = 1.f / (1.f + expf(-(gir + ghr)));
    float z = 1.f / (1.f + expf(-(giz + ghz)));
    float n = tanhf(gin + r * ghn);
    float wn = (1.f - z) * n + z * Wc[(size_t)i * C + j];
    wnewT[(size_t)j * C + i] = wn;   // transposed: element W_new[i][j] at [j*C + i]
}

// ---------------------------------------------------------------- edge scatter into CSR order
__global__ void k_scatter(const int* __restrict__ ei, const float* __restrict__ ew,
                          const float* __restrict__ dinv, int* __restrict__ cursor,
                          int* __restrict__ ssrc, float* __restrict__ snorm, int E) {
    int e = blockIdx.x * blockDim.x + threadIdx.x;
    if (e < E) {
        int s = ei[e], d = ei[E + e];
        float nm = dinv[s] * ew[e] * dinv[d];
        int pos = atomicAdd(&cursor[d], 1);
        ssrc[pos] = s;
        snorm[pos] = nm;
    }
}

// ---------------------------------------------------------------- Xw = X @ W_new^T  (W_new^T in LDS)
__global__ __launch_bounds__(256) void k_xw(const float* __restrict__ X,
                                            const float* __restrict__ wnewT,
                                            float* __restrict__ xw, int N) {
    __shared__ float Wt[C * C];   // 64 KB: Wt[k*C + c] = W_new[c][k]
    int t = threadIdx.x;
    for (int e = t; e < C * C; e += 256) Wt[e] = wnewT[e];
    __syncthreads();

    int r0 = blockIdx.x * 128;
    int r1 = r0 + (t & 63);
    int r2 = r1 + 64;
    int c0 = (t >> 6) * 32;
    const float4* xr1 = (const float4*)(X + (size_t)(r1 < N ? r1 : N - 1) * C);
    const float4* xr2 = (const float4*)(X + (size_t)(r2 < N ? r2 : N - 1) * C);
    float acc1[32], acc2[32];
    #pragma unroll
    for (int c = 0; c < 32; c++) { acc1[c] = 0.f; acc2[c] = 0.f; }

    for (int k4 = 0; k4 < C / 4; k4++) {
        float4 xa = xr1[k4], xb = xr2[k4];
        #pragma unroll
        for (int kk = 0; kk < 4; kk++) {
            float x1 = ((const float*)&xa)[kk];
            float x2 = ((const float*)&xb)[kk];
            const float* wrow = &Wt[(k4 * 4 + kk) * C + c0];
            #pragma unroll
            for (int cc = 0; cc < 32; cc += 4) {
                float4 wv = *(const float4*)(wrow + cc);
                acc1[cc + 0] += x1 * wv.x; acc1[cc + 1] += x1 * wv.y;
                acc1[cc + 2] += x1 * wv.z; acc1[cc + 3] += x1 * wv.w;
                acc2[cc + 0] += x2 * wv.x; acc2[cc + 1] += x2 * wv.y;
                acc2[cc + 2] += x2 * wv.z; acc2[cc + 3] += x2 * wv.w;
            }
        }
    }
    if (r1 < N) {
        float4* o = (float4*)(xw + (size_t)r1 * C + c0);
        #pragma unroll
        for (int cc = 0; cc < 32; cc += 4)
            o[cc >> 2] = make_float4(acc1[cc], acc1[cc + 1], acc1[cc + 2], acc1[cc + 3]);
    }
    if (r2 < N) {
        float4* o = (float4*)(xw + (size_t)r2 * C + c0);
        #pragma unroll
        for (int cc = 0; cc < 32; cc += 4)
            o[cc >> 2] = make_float4(acc2[cc], acc2[cc + 1], acc2[cc + 2], acc2[cc + 3]);
    }
}

// ---------------------------------------------------------------- gather: out[v] = dinv[v]^2*Xw[v] + sum_e nm*Xw[src] + b
__global__ __launch_bounds__(256) void k_gather(const float* __restrict__ xw,
                                                const int* __restrict__ offs,
                                                const int* __restrict__ ssrc,
                                                const float* __restrict__ snorm,
                                                const float* __restrict__ dinv,
                                                const float* __restrict__ b_conv,
                                                float* __restrict__ out, int N) {
    int t = threadIdx.x;
    int v = blockIdx.x * 2 + (t >> 7);
    int c = t & 127;
    if (v >= N) return;
    float dv = dinv[v];
    float acc = dv * dv * xw[(size_t)v * C + c];
    int e0 = offs[v], e1 = offs[v + 1];
    int e = e0;
    for (; e + 1 < e1; e += 2) {
        int sA = ssrc[e], sB = ssrc[e + 1];
        float nA = snorm[e], nB = snorm[e + 1];
        float xA = xw[(size_t)sA * C + c];
        float xB = xw[(size_t)sB * C + c];
        acc += nA * xA + nB * xB;
    }
    if (e < e1) acc += snorm[e] * xw[(size_t)ssrc[e] * C + c];
    out[(size_t)v * C + c] = acc + b_conv[c];
}

// ---------------------------------------------------------------- launcher
extern "C" void kernel_launch(void* const* d_in, const int* in_sizes, int n_in,
                              void* d_out, int out_size, void* d_ws, size_t ws_size,
                              hipStream_t stream) {
    const float* X      = (const float*)d_in[0];
    const float* ew     = (const float*)d_in[1];
    const float* p      = (const float*)d_in[2];
    const float* W_ih   = (const float*)d_in[3];
    const float* W_hh   = (const float*)d_in[4];
    const float* b_ih   = (const float*)d_in[5];
    const float* b_hh   = (const float*)d_in[6];
    const float* W_conv = (const float*)d_in[7];
    const float* b_conv = (const float*)d_in[8];
    const int*   ei     = (const int*)d_in[9];
    const int N = in_sizes[0] / C;
    const int E = in_sizes[1];
    float* out = (float*)d_out;

    char* w = (char*)d_ws;
    auto alloc = [&](size_t bytes) -> void* {
        void* r = (void*)w;
        w += (bytes + 255) & ~(size_t)255;
        return r;
    };
    float* scores = (float*)alloc((size_t)N * 4);
    float* deg    = (float*)alloc((size_t)N * 4);
    float* dinv   = (float*)alloc((size_t)N * 4);
    int*   cnt    = (int*)alloc((size_t)N * 4);
    int*   offs   = (int*)alloc((size_t)(N + 1) * 4);
    int*   cursor = (int*)alloc((size_t)N * 4);
    int*   tidx   = (int*)alloc(C * 4);
    float* gate   = (float*)alloc(C * 4);
    float* xtl    = (float*)alloc((size_t)C * C * 4);
    float* wnewT  = (float*)alloc((size_t)C * C * 4);
    int*   ssrc   = (int*)alloc((size_t)E * 4);
    float* snorm  = (float*)alloc((size_t)E * 4);
    float* xw     = (float*)alloc((size_t)N * C * 4);

    k_init<<<(N + 255) / 256, 256, 0, stream>>>(deg, cnt, N);
    k_scores<<<(N + 3) / 4, 256, 0, stream>>>(X, p, scores, N);
    k_deghist<<<(E + 255) / 256, 256, 0, stream>>>(ei, ew, deg, cnt, E);
    k_topk<<<1, TKT, 0, stream>>>(scores, p, tidx, gate, N);
    k_scan<<<1, SCT, 0, stream>>>(cnt, deg, offs, cursor, dinv, N, E);
    k_xtilde<<<(C * C) / 256, 256, 0, stream>>>(X, tidx, gate, xtl);
    k_gru<<<C / 2, 256, 0, stream>>>(xtl, W_conv, W_ih, W_hh, b_ih, b_hh, wnewT);
    k_scatter<<<(E + 255) / 256, 256, 0, stream>>>(ei, ew, dinv, cursor, ssrc, snorm, E);
    k_xw<<<(N + 127) / 128, 256, 0, stream>>>(X, wnewT, xw, N);
    k_gather<<<(N + 1) / 2, 256, 0, stream>>>(xw, offs, ssrc, snorm, dinv, b_conv, out, N);
}

// Round 2
// 620.758 us; speedup vs baseline: 1.4835x; 1.4835x over previous
//
#include <hip/hip_runtime.h>
#include <math.h>

#define C 128
#define HB 2048          // histogram buckets (top 11 bits of ordered float)
#define NS 4096          // candidate capacity (pow2 for bitonic)

__device__ inline unsigned ord_f32(float f) {
    unsigned u = __float_as_uint(f);
    return u ^ ((u & 0x80000000u) ? 0xFFFFFFFFu : 0x80000000u);
}
__device__ inline float unord_f32(unsigned u) {
    return __uint_as_float(u ^ ((u & 0x80000000u) ? 0x80000000u : 0xFFFFFFFFu));
}

// ---------------------------------------------------------------- init: deg=1 (self loop), cnt=0, hist=0, nc=0
__global__ void k_init(float* __restrict__ deg, int* __restrict__ cnt,
                       int* __restrict__ hist, int* __restrict__ nc, int N) {
    int i = blockIdx.x * blockDim.x + threadIdx.x;
    if (i < N) { deg[i] = 1.0f; cnt[i] = 0; }
    if (i < HB) hist[i] = 0;
    if (i == 0) nc[0] = 0;
}

// ---------------------------------------------------------------- scores: s[i] = X[i,:] . p
__global__ void k_scores(const float* __restrict__ X, const float* __restrict__ p,
                         float* __restrict__ scores, int N) {
    int wid  = (int)((blockIdx.x * (size_t)blockDim.x + threadIdx.x) >> 6);
    int lane = threadIdx.x & 63;
    if (wid >= N) return;
    const float* xr = X + (size_t)wid * C;
    float a = xr[lane] * p[lane] + xr[lane + 64] * p[lane + 64];
    #pragma unroll
    for (int o = 32; o; o >>= 1) a += __shfl_down(a, o);
    if (lane == 0) scores[wid] = a;
}

// ---------------------------------------------------------------- LDS histogram of score buckets
#define HTB 1024
__global__ __launch_bounds__(HTB) void k_hist(const float* __restrict__ scores,
                                              int* __restrict__ hist, int N) {
    __shared__ int lh[HB];
    int t = threadIdx.x;
    for (int i = t; i < HB; i += HTB) lh[i] = 0;
    __syncthreads();
    for (int i = blockIdx.x * HTB + t; i < N; i += gridDim.x * HTB)
        atomicAdd(&lh[ord_f32(scores[i]) >> 21], 1);
    __syncthreads();
    for (int i = t; i < HB; i += HTB) {
        int v = lh[i];
        if (v) atomicAdd(&hist[i], v);
    }
}

// ---------------------------------------------------------------- threshold bucket: suffix-from-top crosses 128
__global__ __launch_bounds__(256) void k_thresh(const int* __restrict__ hist, int* __restrict__ Tout) {
    __shared__ int sc[256];
    int t = threadIdx.x;
    int loc[8];
    int sum = 0;
    #pragma unroll
    for (int s = 0; s < 8; s++) {
        int b = HB - 1 - (t * 8 + s);
        loc[s] = hist[b];
        sum += loc[s];
    }
    sc[t] = sum;
    __syncthreads();
    for (int off = 1; off < 256; off <<= 1) {
        int v = (t >= off) ? sc[t - off] : 0;
        __syncthreads();
        sc[t] += v;
        __syncthreads();
    }
    int run = sc[t] - sum;   // exclusive prefix over reversed buckets
    #pragma unroll
    for (int s = 0; s < 8; s++) {
        int b = HB - 1 - (t * 8 + s);
        int nr = run + loc[s];
        if (run < C && nr >= C) *Tout = b;
        run = nr;
    }
}

// ---------------------------------------------------------------- collect candidates with bucket >= T
__global__ void k_filter(const float* __restrict__ scores, const int* __restrict__ Tptr,
                         int* __restrict__ nc, unsigned long long* __restrict__ cand, int N) {
    int i = blockIdx.x * blockDim.x + threadIdx.x;
    if (i >= N) return;
    unsigned u = ord_f32(scores[i]);
    if ((int)(u >> 21) >= *Tptr) {
        int pos = atomicAdd(nc, 1);
        if (pos < NS)
            cand[pos] = ((unsigned long long)u << 32) | (unsigned)(~(unsigned)i);
    }
}

// ---------------------------------------------------------------- bitonic sort candidates desc, emit top-128
__global__ __launch_bounds__(1024) void k_sel(const unsigned long long* __restrict__ cand,
                                              const int* __restrict__ nc,
                                              const float* __restrict__ p,
                                              int* __restrict__ tidx, float* __restrict__ gate) {
    __shared__ unsigned long long sk[NS];
    __shared__ float red[16];
    __shared__ float s_pn;
    int t = threadIdx.x;
    int M = *nc; if (M > NS) M = NS;
    for (int i = t; i < NS; i += 1024) sk[i] = (i < M) ? cand[i] : 0ULL;
    float pv = 0.f;
    if (t < C) { float x = p[t]; pv = x * x; }
    #pragma unroll
    for (int o = 32; o; o >>= 1) pv += __shfl_down(pv, o);
    if ((t & 63) == 0) red[t >> 6] = pv;
    __syncthreads();
    if (t == 0) {
        float s = 0.f;
        for (int i = 0; i < 16; i++) s += red[i];
        s_pn = sqrtf(s);
    }
    for (int k = 2; k <= NS; k <<= 1) {
        for (int j = k >> 1; j > 0; j >>= 1) {
            __syncthreads();
            #pragma unroll
            for (int s = 0; s < NS / 1024; s++) {
                int idx = t + s * 1024;
                int l = idx ^ j;
                if (l > idx) {
                    unsigned long long a = sk[idx], b = sk[l];
                    bool desc = (idx & k) == 0;
                    if (desc ? (a < b) : (a > b)) { sk[idx] = b; sk[l] = a; }
                }
            }
        }
    }
    __syncthreads();
    if (t < C) {
        unsigned long long g = sk[t];
        tidx[t] = (int)(~(unsigned)(g & 0xFFFFFFFFull));
        gate[t] = tanhf(unord_f32((unsigned)(g >> 32)) / s_pn);
    }
}

// ---------------------------------------------------------------- degree + count histogram over edges
__global__ void k_deghist(const int* __restrict__ ei, const float* __restrict__ ew,
                          float* __restrict__ deg, int* __restrict__ cnt, int E) {
    int e = blockIdx.x * blockDim.x + threadIdx.x;
    if (e < E) {
        int d = ei[E + e];
        atomicAdd(&deg[d], ew[e]);
        atomicAdd(&cnt[d], 1);
    }
}

// ---------------------------------------------------------------- X_tilde = X[idx] * gate
__global__ void k_xtilde(const float* __restrict__ X, const int* __restrict__ tidx,
                         const float* __restrict__ gate, float* __restrict__ xtl) {
    int gid = blockIdx.x * blockDim.x + threadIdx.x;
    int i = gid >> 7, k = gid & 127;
    xtl[gid] = X[(size_t)tidx[i] * C + k] * gate[i];
}

// ---------------------------------------------------------------- scan: offsets, cursor, dinv
#define SCT 1024
#define SCC 49
__global__ __launch_bounds__(SCT) void k_scan(const int* __restrict__ cnt, const float* __restrict__ deg,
                                              int* __restrict__ offs, int* __restrict__ cursor,
                                              float* __restrict__ dinv, int N, int E) {
    __shared__ int sc[SCT];
    int t = threadIdx.x;
    int start = t * SCC;
    int sum = 0;
    for (int s = 0; s < SCC; s++) {
        int i = start + s;
        if (i < N) sum += cnt[i];
    }
    sc[t] = sum;
    __syncthreads();
    for (int off = 1; off < SCT; off <<= 1) {
        int v = (t >= off) ? sc[t - off] : 0;
        __syncthreads();
        sc[t] += v;
        __syncthreads();
    }
    int run = sc[t] - sum;
    for (int s = 0; s < SCC; s++) {
        int i = start + s;
        if (i < N) {
            offs[i] = run;
            cursor[i] = run;
            run += cnt[i];
            dinv[i] = rsqrtf(deg[i]);
        }
    }
    if (t == 0) offs[N] = E;
}

// ---------------------------------------------------------------- GRU step -> W_new^T  (layout [k][c])
__global__ __launch_bounds__(256) void k_gru(const float* __restrict__ xtl, const float* __restrict__ Wc,
                                             const float* __restrict__ W_ih, const float* __restrict__ W_hh,
                                             const float* __restrict__ b_ih, const float* __restrict__ b_hh,
                                             float* __restrict__ wnewT) {
    int t = threadIdx.x;
    int i = t & 127;
    int j = blockIdx.x * 2 + (t >> 7);
    const float4* xr   = (const float4*)(xtl + (size_t)i * C);
    const float4* hr   = (const float4*)(Wc + (size_t)i * C);
    const float4* wri  = (const float4*)(W_ih + (size_t)j * C);
    const float4* wzi  = (const float4*)(W_ih + (size_t)(C + j) * C);
    const float4* wni  = (const float4*)(W_ih + (size_t)(2 * C + j) * C);
    const float4* wrh  = (const float4*)(W_hh + (size_t)j * C);
    const float4* wzh  = (const float4*)(W_hh + (size_t)(C + j) * C);
    const float4* wnh  = (const float4*)(W_hh + (size_t)(2 * C + j) * C);
    float gir = 0, giz = 0, gin = 0, ghr = 0, ghz = 0, ghn = 0;
    #pragma unroll 8
    for (int k4 = 0; k4 < C / 4; k4++) {
        float4 x = xr[k4], h = hr[k4], a;
        a = wri[k4]; gir += x.x * a.x + x.y * a.y + x.z * a.z + x.w * a.w;
        a = wzi[k4]; giz += x.x * a.x + x.y * a.y + x.z * a.z + x.w * a.w;
        a = wni[k4]; gin += x.x * a.x + x.y * a.y + x.z * a.z + x.w * a.w;
        a = wrh[k4]; ghr += h.x * a.x + h.y * a.y + h.z * a.z + h.w * a.w;
        a = wzh[k4]; ghz += h.x * a.x + h.y * a.y + h.z * a.z + h.w * a.w;
        a = wnh[k4]; ghn += h.x * a.x + h.y * a.y + h.z * a.z + h.w * a.w;
    }
    gir += b_ih[j];         ghr += b_hh[j];
    giz += b_ih[C + j];     ghz += b_hh[C + j];
    gin += b_ih[2 * C + j]; ghn += b_hh[2 * C + j];
    float r = 1.f / (1.f + expf(-(gir + ghr)));
    float z = 1.f / (1.f + expf(-(giz + ghz)));
    float n = tanhf(gin + r * ghn);
    float wn = (1.f - z) * n + z * Wc[(size_t)i * C + j];
    wnewT[(size_t)j * C + i] = wn;
}

// ---------------------------------------------------------------- edge scatter into CSR order (packed 8B)
__global__ void k_scatter(const int* __restrict__ ei, const float* __restrict__ ew,
                          const float* __restrict__ dinv, int* __restrict__ cursor,
                          unsigned long long* __restrict__ epack, int E) {
    int e = blockIdx.x * blockDim.x + threadIdx.x;
    if (e < E) {
        int s = ei[e], d = ei[E + e];
        float nm = dinv[s] * ew[e] * dinv[d];
        int pos = atomicAdd(&cursor[d], 1);
        epack[pos] = ((unsigned long long)__float_as_uint(nm) << 32) | (unsigned)s;
    }
}

// ---------------------------------------------------------------- Xw = X @ W_new^T  (W_new^T in LDS)
__global__ __launch_bounds__(256) void k_xw(const float* __restrict__ X,
                                            const float* __restrict__ wnewT,
                                            float* __restrict__ xw, int N) {
    __shared__ float Wt[C * C];
    int t = threadIdx.x;
    for (int e = t; e < C * C; e += 256) Wt[e] = wnewT[e];
    __syncthreads();

    int r0 = blockIdx.x * 128;
    int r1 = r0 + (t & 63);
    int r2 = r1 + 64;
    int c0 = (t >> 6) * 32;
    const float4* xr1 = (const float4*)(X + (size_t)(r1 < N ? r1 : N - 1) * C);
    const float4* xr2 = (const float4*)(X + (size_t)(r2 < N ? r2 : N - 1) * C);
    float acc1[32], acc2[32];
    #pragma unroll
    for (int c = 0; c < 32; c++) { acc1[c] = 0.f; acc2[c] = 0.f; }

    for (int k4 = 0; k4 < C / 4; k4++) {
        float4 xa = xr1[k4], xb = xr2[k4];
        #pragma unroll
        for (int kk = 0; kk < 4; kk++) {
            float x1 = ((const float*)&xa)[kk];
            float x2 = ((const float*)&xb)[kk];
            const float* wrow = &Wt[(k4 * 4 + kk) * C + c0];
            #pragma unroll
            for (int cc = 0; cc < 32; cc += 4) {
                float4 wv = *(const float4*)(wrow + cc);
                acc1[cc + 0] += x1 * wv.x; acc1[cc + 1] += x1 * wv.y;
                acc1[cc + 2] += x1 * wv.z; acc1[cc + 3] += x1 * wv.w;
                acc2[cc + 0] += x2 * wv.x; acc2[cc + 1] += x2 * wv.y;
                acc2[cc + 2] += x2 * wv.z; acc2[cc + 3] += x2 * wv.w;
            }
        }
    }
    if (r1 < N) {
        float4* o = (float4*)(xw + (size_t)r1 * C + c0);
        #pragma unroll
        for (int cc = 0; cc < 32; cc += 4)
            o[cc >> 2] = make_float4(acc1[cc], acc1[cc + 1], acc1[cc + 2], acc1[cc + 3]);
    }
    if (r2 < N) {
        float4* o = (float4*)(xw + (size_t)r2 * C + c0);
        #pragma unroll
        for (int cc = 0; cc < 32; cc += 4)
            o[cc >> 2] = make_float4(acc2[cc], acc2[cc + 1], acc2[cc + 2], acc2[cc + 3]);
    }
}

// ---------------------------------------------------------------- gather: out[v] = dinv^2*Xw[v] + sum nm*Xw[src] + b
__global__ __launch_bounds__(256) void k_gather(const float* __restrict__ xw,
                                                const int* __restrict__ offs,
                                                const unsigned long long* __restrict__ epack,
                                                const float* __restrict__ dinv,
                                                const float* __restrict__ b_conv,
                                                float* __restrict__ out, int N) {
    int t = threadIdx.x;
    int v = blockIdx.x * 2 + (t >> 7);
    int c = t & 127;
    if (v >= N) return;
    float dv = dinv[v];
    float acc = dv * dv * xw[(size_t)v * C + c];
    int e0 = offs[v], e1 = offs[v + 1];
    int e = e0;
    for (; e + 1 < e1; e += 2) {
        unsigned long long pA = epack[e], pB = epack[e + 1];
        float xA = xw[(size_t)(unsigned)(pA & 0xFFFFFFFFull) * C + c];
        float xB = xw[(size_t)(unsigned)(pB & 0xFFFFFFFFull) * C + c];
        acc += __uint_as_float((unsigned)(pA >> 32)) * xA
             + __uint_as_float((unsigned)(pB >> 32)) * xB;
    }
    if (e < e1) {
        unsigned long long pA = epack[e];
        acc += __uint_as_float((unsigned)(pA >> 32))
             * xw[(size_t)(unsigned)(pA & 0xFFFFFFFFull) * C + c];
    }
    out[(size_t)v * C + c] = acc + b_conv[c];
}

// ---------------------------------------------------------------- launcher
extern "C" void kernel_launch(void* const* d_in, const int* in_sizes, int n_in,
                              void* d_out, int out_size, void* d_ws, size_t ws_size,
                              hipStream_t stream) {
    const float* X      = (const float*)d_in[0];
    const float* ew     = (const float*)d_in[1];
    const float* p      = (const float*)d_in[2];
    const float* W_ih   = (const float*)d_in[3];
    const float* W_hh   = (const float*)d_in[4];
    const float* b_ih   = (const float*)d_in[5];
    const float* b_hh   = (const float*)d_in[6];
    const float* W_conv = (const float*)d_in[7];
    const float* b_conv = (const float*)d_in[8];
    const int*   ei     = (const int*)d_in[9];
    const int N = in_sizes[0] / C;
    const int E = in_sizes[1];
    float* out = (float*)d_out;

    char* w = (char*)d_ws;
    auto alloc = [&](size_t bytes) -> void* {
        void* r = (void*)w;
        w += (bytes + 255) & ~(size_t)255;
        return r;
    };
    float* scores = (float*)alloc((size_t)N * 4);
    float* deg    = (float*)alloc((size_t)N * 4);
    float* dinv   = (float*)alloc((size_t)N * 4);
    int*   cnt    = (int*)alloc((size_t)N * 4);
    int*   offs   = (int*)alloc((size_t)(N + 1) * 4);
    int*   cursor = (int*)alloc((size_t)N * 4);
    int*   hist   = (int*)alloc(HB * 4);
    int*   nc     = (int*)alloc(256);
    int*   Tbuf   = (int*)alloc(256);
    unsigned long long* cand = (unsigned long long*)alloc((size_t)NS * 8);
    int*   tidx   = (int*)alloc(C * 4);
    float* gate   = (float*)alloc(C * 4);
    float* xtl    = (float*)alloc((size_t)C * C * 4);
    float* wnewT  = (float*)alloc((size_t)C * C * 4);
    unsigned long long* epack = (unsigned long long*)alloc((size_t)E * 8);
    float* xw     = (float*)alloc((size_t)N * C * 4);

    k_init<<<(N + 255) / 256, 256, 0, stream>>>(deg, cnt, hist, nc, N);
    k_scores<<<(N + 3) / 4, 256, 0, stream>>>(X, p, scores, N);
    k_deghist<<<(E + 255) / 256, 256, 0, stream>>>(ei, ew, deg, cnt, E);
    k_hist<<<32, HTB, 0, stream>>>(scores, hist, N);
    k_thresh<<<1, 256, 0, stream>>>(hist, Tbuf);
    k_filter<<<(N + 255) / 256, 256, 0, stream>>>(scores, Tbuf, nc, cand, N);
    k_sel<<<1, 1024, 0, stream>>>(cand, nc, p, tidx, gate);
    k_xtilde<<<(C * C) / 256, 256, 0, stream>>>(X, tidx, gate, xtl);
    k_gru<<<C / 2, 256, 0, stream>>>(xtl, W_conv, W_ih, W_hh, b_ih, b_hh, wnewT);
    k_scan<<<1, SCT, 0, stream>>>(cnt, deg, offs, cursor, dinv, N, E);
    k_scatter<<<(E + 255) / 256, 256, 0, stream>>>(ei, ew, dinv, cursor, epack, E);
    k_xw<<<(N + 127) / 128, 256, 0, stream>>>(X, wnewT, xw, N);
    k_gather<<<(N + 1) / 2, 256, 0, stream>>>(xw, offs, epack, dinv, b_conv, out, N);
}

// Round 3
// 430.448 us; speedup vs baseline: 2.1394x; 1.4421x over previous
//
#include <hip/hip_runtime.h>
#include <math.h>

#define C 128
#define HB 2048          // histogram buckets (top 11 bits of ordered float)
#define NS 4096          // candidate capacity (pow2 for bitonic)

__device__ inline unsigned ord_f32(float f) {
    unsigned u = __float_as_uint(f);
    return u ^ ((u & 0x80000000u) ? 0xFFFFFFFFu : 0x80000000u);
}
__device__ inline float unord_f32(unsigned u) {
    return __uint_as_float(u ^ ((u & 0x80000000u) ? 0x80000000u : 0xFFFFFFFFu));
}

// ---------------------------------------------------------------- init: deg=1 (self loop), cnt=0, hist=0, nc=0
__global__ void k_init(float* __restrict__ deg, int* __restrict__ cnt,
                       int* __restrict__ hist, int* __restrict__ nc, int N) {
    int i = blockIdx.x * blockDim.x + threadIdx.x;
    if (i < N) { deg[i] = 1.0f; cnt[i] = 0; }
    if (i < HB) hist[i] = 0;
    if (i == 0) nc[0] = 0;
}

// ---------------------------------------------------------------- scores: s[i] = X[i,:] . p
__global__ void k_scores(const float* __restrict__ X, const float* __restrict__ p,
                         float* __restrict__ scores, int N) {
    int wid  = (int)((blockIdx.x * (size_t)blockDim.x + threadIdx.x) >> 6);
    int lane = threadIdx.x & 63;
    if (wid >= N) return;
    const float* xr = X + (size_t)wid * C;
    float a = xr[lane] * p[lane] + xr[lane + 64] * p[lane + 64];
    #pragma unroll
    for (int o = 32; o; o >>= 1) a += __shfl_down(a, o);
    if (lane == 0) scores[wid] = a;
}

// ---------------------------------------------------------------- LDS histogram of score buckets
#define HTB 1024
__global__ __launch_bounds__(HTB) void k_hist(const float* __restrict__ scores,
                                              int* __restrict__ hist, int N) {
    __shared__ int lh[HB];
    int t = threadIdx.x;
    for (int i = t; i < HB; i += HTB) lh[i] = 0;
    __syncthreads();
    for (int i = blockIdx.x * HTB + t; i < N; i += gridDim.x * HTB)
        atomicAdd(&lh[ord_f32(scores[i]) >> 21], 1);
    __syncthreads();
    for (int i = t; i < HB; i += HTB) {
        int v = lh[i];
        if (v) atomicAdd(&hist[i], v);
    }
}

// ---------------------------------------------------------------- threshold bucket: suffix-from-top crosses 128
__global__ __launch_bounds__(256) void k_thresh(const int* __restrict__ hist, int* __restrict__ Tout) {
    __shared__ int sc[256];
    int t = threadIdx.x;
    int loc[8];
    int sum = 0;
    #pragma unroll
    for (int s = 0; s < 8; s++) {
        int b = HB - 1 - (t * 8 + s);
        loc[s] = hist[b];
        sum += loc[s];
    }
    sc[t] = sum;
    __syncthreads();
    for (int off = 1; off < 256; off <<= 1) {
        int v = (t >= off) ? sc[t - off] : 0;
        __syncthreads();
        sc[t] += v;
        __syncthreads();
    }
    int run = sc[t] - sum;   // exclusive prefix over reversed buckets
    #pragma unroll
    for (int s = 0; s < 8; s++) {
        int b = HB - 1 - (t * 8 + s);
        int nr = run + loc[s];
        if (run < C && nr >= C) *Tout = b;
        run = nr;
    }
}

// ---------------------------------------------------------------- collect candidates with bucket >= T
__global__ void k_filter(const float* __restrict__ scores, const int* __restrict__ Tptr,
                         int* __restrict__ nc, unsigned long long* __restrict__ cand, int N) {
    int i = blockIdx.x * blockDim.x + threadIdx.x;
    if (i >= N) return;
    unsigned u = ord_f32(scores[i]);
    if ((int)(u >> 21) >= *Tptr) {
        int pos = atomicAdd(nc, 1);
        if (pos < NS)
            cand[pos] = ((unsigned long long)u << 32) | (unsigned)(~(unsigned)i);
    }
}

// ---------------------------------------------------------------- bitonic sort candidates desc, emit top-128
__global__ __launch_bounds__(1024) void k_sel(const unsigned long long* __restrict__ cand,
                                              const int* __restrict__ nc,
                                              const float* __restrict__ p,
                                              int* __restrict__ tidx, float* __restrict__ gate) {
    __shared__ unsigned long long sk[NS];
    __shared__ float red[16];
    __shared__ float s_pn;
    int t = threadIdx.x;
    int M = *nc; if (M > NS) M = NS;
    for (int i = t; i < NS; i += 1024) sk[i] = (i < M) ? cand[i] : 0ULL;
    float pv = 0.f;
    if (t < C) { float x = p[t]; pv = x * x; }
    #pragma unroll
    for (int o = 32; o; o >>= 1) pv += __shfl_down(pv, o);
    if ((t & 63) == 0) red[t >> 6] = pv;
    __syncthreads();
    if (t == 0) {
        float s = 0.f;
        for (int i = 0; i < 16; i++) s += red[i];
        s_pn = sqrtf(s);
    }
    for (int k = 2; k <= NS; k <<= 1) {
        for (int j = k >> 1; j > 0; j >>= 1) {
            __syncthreads();
            #pragma unroll
            for (int s = 0; s < NS / 1024; s++) {
                int idx = t + s * 1024;
                int l = idx ^ j;
                if (l > idx) {
                    unsigned long long a = sk[idx], b = sk[l];
                    bool desc = (idx & k) == 0;
                    if (desc ? (a < b) : (a > b)) { sk[idx] = b; sk[l] = a; }
                }
            }
        }
    }
    __syncthreads();
    if (t < C) {
        unsigned long long g = sk[t];
        tidx[t] = (int)(~(unsigned)(g & 0xFFFFFFFFull));
        gate[t] = tanhf(unord_f32((unsigned)(g >> 32)) / s_pn);
    }
}

// ---------------------------------------------------------------- degree + count histogram over edges
__global__ void k_deghist(const int* __restrict__ ei, const float* __restrict__ ew,
                          float* __restrict__ deg, int* __restrict__ cnt, int E) {
    int e = blockIdx.x * blockDim.x + threadIdx.x;
    if (e < E) {
        int d = ei[E + e];
        atomicAdd(&deg[d], ew[e]);
        atomicAdd(&cnt[d], 1);
    }
}

// ---------------------------------------------------------------- X_tilde = X[idx] * gate
__global__ void k_xtilde(const float* __restrict__ X, const int* __restrict__ tidx,
                         const float* __restrict__ gate, float* __restrict__ xtl) {
    int gid = blockIdx.x * blockDim.x + threadIdx.x;
    int i = gid >> 7, k = gid & 127;
    xtl[gid] = X[(size_t)tidx[i] * C + k] * gate[i];
}

// ---------------------------------------------------------------- hierarchical scan, phase A: per-block scan
__global__ __launch_bounds__(256) void k_scan1(const int* __restrict__ cnt,
                                               int* __restrict__ pref, int* __restrict__ bsum, int N) {
    __shared__ int sc[256];
    int t = threadIdx.x;
    int i = blockIdx.x * 256 + t;
    int v = (i < N) ? cnt[i] : 0;
    sc[t] = v;
    __syncthreads();
    for (int off = 1; off < 256; off <<= 1) {
        int u = (t >= off) ? sc[t - off] : 0;
        __syncthreads();
        sc[t] += u;
        __syncthreads();
    }
    if (i < N) pref[i] = sc[t] - v;          // exclusive within block
    if (t == 255) bsum[blockIdx.x] = sc[255];
}

// ---------------------------------------------------------------- phase B: scan block sums (nb <= 256)
__global__ __launch_bounds__(256) void k_scan2(int* __restrict__ bsum, int nb) {
    __shared__ int sc[256];
    int t = threadIdx.x;
    int v = (t < nb) ? bsum[t] : 0;
    sc[t] = v;
    __syncthreads();
    for (int off = 1; off < 256; off <<= 1) {
        int u = (t >= off) ? sc[t - off] : 0;
        __syncthreads();
        sc[t] += u;
        __syncthreads();
    }
    if (t < nb) bsum[t] = sc[t] - v;         // exclusive in place
}

// ---------------------------------------------------------------- phase C: finalize offs/cursor/dinv
__global__ __launch_bounds__(256) void k_scan3(const int* __restrict__ pref, const int* __restrict__ bsum,
                                               const float* __restrict__ deg,
                                               int* __restrict__ offs, int* __restrict__ cursor,
                                               float* __restrict__ dinv, int N, int E) {
    int i = blockIdx.x * 256 + threadIdx.x;
    if (i < N) {
        int o = bsum[blockIdx.x] + pref[i];
        offs[i] = o;
        cursor[i] = o;
        dinv[i] = rsqrtf(deg[i]);
    }
    if (i == 0) offs[N] = E;
}

// ---------------------------------------------------------------- GRU step -> W_new^T  (layout [k][c])
__global__ __launch_bounds__(256) void k_gru(const float* __restrict__ xtl, const float* __restrict__ Wc,
                                             const float* __restrict__ W_ih, const float* __restrict__ W_hh,
                                             const float* __restrict__ b_ih, const float* __restrict__ b_hh,
                                             float* __restrict__ wnewT) {
    int t = threadIdx.x;
    int i = t & 127;
    int j = blockIdx.x * 2 + (t >> 7);
    const float4* xr   = (const float4*)(xtl + (size_t)i * C);
    const float4* hr   = (const float4*)(Wc + (size_t)i * C);
    const float4* wri  = (const float4*)(W_ih + (size_t)j * C);
    const float4* wzi  = (const float4*)(W_ih + (size_t)(C + j) * C);
    const float4* wni  = (const float4*)(W_ih + (size_t)(2 * C + j) * C);
    const float4* wrh  = (const float4*)(W_hh + (size_t)j * C);
    const float4* wzh  = (const float4*)(W_hh + (size_t)(C + j) * C);
    const float4* wnh  = (const float4*)(W_hh + (size_t)(2 * C + j) * C);
    float gir = 0, giz = 0, gin = 0, ghr = 0, ghz = 0, ghn = 0;
    #pragma unroll 8
    for (int k4 = 0; k4 < C / 4; k4++) {
        float4 x = xr[k4], h = hr[k4], a;
        a = wri[k4]; gir += x.x * a.x + x.y * a.y + x.z * a.z + x.w * a.w;
        a = wzi[k4]; giz += x.x * a.x + x.y * a.y + x.z * a.z + x.w * a.w;
        a = wni[k4]; gin += x.x * a.x + x.y * a.y + x.z * a.z + x.w * a.w;
        a = wrh[k4]; ghr += h.x * a.x + h.y * a.y + h.z * a.z + h.w * a.w;
        a = wzh[k4]; ghz += h.x * a.x + h.y * a.y + h.z * a.z + h.w * a.w;
        a = wnh[k4]; ghn += h.x * a.x + h.y * a.y + h.z * a.z + h.w * a.w;
    }
    gir += b_ih[j];         ghr += b_hh[j];
    giz += b_ih[C + j];     ghz += b_hh[C + j];
    gin += b_ih[2 * C + j]; ghn += b_hh[2 * C + j];
    float r = 1.f / (1.f + expf(-(gir + ghr)));
    float z = 1.f / (1.f + expf(-(giz + ghz)));
    float n = tanhf(gin + r * ghn);
    float wn = (1.f - z) * n + z * Wc[(size_t)i * C + j];
    wnewT[(size_t)j * C + i] = wn;
}

// ---------------------------------------------------------------- edge scatter into CSR order (packed 8B)
__global__ void k_scatter(const int* __restrict__ ei, const float* __restrict__ ew,
                          const float* __restrict__ dinv, int* __restrict__ cursor,
                          unsigned long long* __restrict__ epack, int E) {
    int e = blockIdx.x * blockDim.x + threadIdx.x;
    if (e < E) {
        int s = ei[e], d = ei[E + e];
        float nm = dinv[s] * ew[e] * dinv[d];
        int pos = atomicAdd(&cursor[d], 1);
        epack[pos] = ((unsigned long long)__float_as_uint(nm) << 32) | (unsigned)s;
    }
}

// ---------------------------------------------------------------- Xw = X @ W_new^T  (W_new^T in LDS)
__global__ __launch_bounds__(256) void k_xw(const float* __restrict__ X,
                                            const float* __restrict__ wnewT,
                                            float* __restrict__ xw, int N) {
    __shared__ float Wt[C * C];
    int t = threadIdx.x;
    for (int e = t; e < C * C; e += 256) Wt[e] = wnewT[e];
    __syncthreads();

    int r0 = blockIdx.x * 128;
    int r1 = r0 + (t & 63);
    int r2 = r1 + 64;
    int c0 = (t >> 6) * 32;
    const float4* xr1 = (const float4*)(X + (size_t)(r1 < N ? r1 : N - 1) * C);
    const float4* xr2 = (const float4*)(X + (size_t)(r2 < N ? r2 : N - 1) * C);
    float acc1[32], acc2[32];
    #pragma unroll
    for (int c = 0; c < 32; c++) { acc1[c] = 0.f; acc2[c] = 0.f; }

    for (int k4 = 0; k4 < C / 4; k4++) {
        float4 xa = xr1[k4], xb = xr2[k4];
        #pragma unroll
        for (int kk = 0; kk < 4; kk++) {
            float x1 = ((const float*)&xa)[kk];
            float x2 = ((const float*)&xb)[kk];
            const float* wrow = &Wt[(k4 * 4 + kk) * C + c0];
            #pragma unroll
            for (int cc = 0; cc < 32; cc += 4) {
                float4 wv = *(const float4*)(wrow + cc);
                acc1[cc + 0] += x1 * wv.x; acc1[cc + 1] += x1 * wv.y;
                acc1[cc + 2] += x1 * wv.z; acc1[cc + 3] += x1 * wv.w;
                acc2[cc + 0] += x2 * wv.x; acc2[cc + 1] += x2 * wv.y;
                acc2[cc + 2] += x2 * wv.z; acc2[cc + 3] += x2 * wv.w;
            }
        }
    }
    if (r1 < N) {
        float4* o = (float4*)(xw + (size_t)r1 * C + c0);
        #pragma unroll
        for (int cc = 0; cc < 32; cc += 4)
            o[cc >> 2] = make_float4(acc1[cc], acc1[cc + 1], acc1[cc + 2], acc1[cc + 3]);
    }
    if (r2 < N) {
        float4* o = (float4*)(xw + (size_t)r2 * C + c0);
        #pragma unroll
        for (int cc = 0; cc < 32; cc += 4)
            o[cc >> 2] = make_float4(acc2[cc], acc2[cc + 1], acc2[cc + 2], acc2[cc + 3]);
    }
}

// ---------------------------------------------------------------- gather: out[v] = dinv^2*Xw[v] + sum nm*Xw[src] + b
__global__ __launch_bounds__(256) void k_gather(const float* __restrict__ xw,
                                                const int* __restrict__ offs,
                                                const unsigned long long* __restrict__ epack,
                                                const float* __restrict__ dinv,
                                                const float* __restrict__ b_conv,
                                                float* __restrict__ out, int N) {
    int t = threadIdx.x;
    int v = blockIdx.x * 2 + (t >> 7);
    int c = t & 127;
    if (v >= N) return;
    float dv = dinv[v];
    float acc = dv * dv * xw[(size_t)v * C + c];
    int e0 = offs[v], e1 = offs[v + 1];
    int e = e0;
    for (; e + 1 < e1; e += 2) {
        unsigned long long pA = epack[e], pB = epack[e + 1];
        float xA = xw[(size_t)(unsigned)(pA & 0xFFFFFFFFull) * C + c];
        float xB = xw[(size_t)(unsigned)(pB & 0xFFFFFFFFull) * C + c];
        acc += __uint_as_float((unsigned)(pA >> 32)) * xA
             + __uint_as_float((unsigned)(pB >> 32)) * xB;
    }
    if (e < e1) {
        unsigned long long pA = epack[e];
        acc += __uint_as_float((unsigned)(pA >> 32))
             * xw[(size_t)(unsigned)(pA & 0xFFFFFFFFull) * C + c];
    }
    out[(size_t)v * C + c] = acc + b_conv[c];
}

// ---------------------------------------------------------------- launcher
extern "C" void kernel_launch(void* const* d_in, const int* in_sizes, int n_in,
                              void* d_out, int out_size, void* d_ws, size_t ws_size,
                              hipStream_t stream) {
    const float* X      = (const float*)d_in[0];
    const float* ew     = (const float*)d_in[1];
    const float* p      = (const float*)d_in[2];
    const float* W_ih   = (const float*)d_in[3];
    const float* W_hh   = (const float*)d_in[4];
    const float* b_ih   = (const float*)d_in[5];
    const float* b_hh   = (const float*)d_in[6];
    const float* W_conv = (const float*)d_in[7];
    const float* b_conv = (const float*)d_in[8];
    const int*   ei     = (const int*)d_in[9];
    const int N = in_sizes[0] / C;
    const int E = in_sizes[1];
    float* out = (float*)d_out;
    const int NB = (N + 255) / 256;   // scan blocks (196 for N=50000)

    char* w = (char*)d_ws;
    auto alloc = [&](size_t bytes) -> void* {
        void* r = (void*)w;
        w += (bytes + 255) & ~(size_t)255;
        return r;
    };
    float* scores = (float*)alloc((size_t)N * 4);
    float* deg    = (float*)alloc((size_t)N * 4);
    float* dinv   = (float*)alloc((size_t)N * 4);
    int*   cnt    = (int*)alloc((size_t)N * 4);
    int*   offs   = (int*)alloc((size_t)(N + 1) * 4);
    int*   cursor = (int*)alloc((size_t)N * 4);
    int*   pref   = (int*)alloc((size_t)N * 4);
    int*   bsum   = (int*)alloc((size_t)NB * 4);
    int*   hist   = (int*)alloc(HB * 4);
    int*   nc     = (int*)alloc(256);
    int*   Tbuf   = (int*)alloc(256);
    unsigned long long* cand = (unsigned long long*)alloc((size_t)NS * 8);
    int*   tidx   = (int*)alloc(C * 4);
    float* gate   = (float*)alloc(C * 4);
    float* xtl    = (float*)alloc((size_t)C * C * 4);
    float* wnewT  = (float*)alloc((size_t)C * C * 4);
    unsigned long long* epack = (unsigned long long*)alloc((size_t)E * 8);
    float* xw     = (float*)alloc((size_t)N * C * 4);

    k_init<<<(N + 255) / 256, 256, 0, stream>>>(deg, cnt, hist, nc, N);
    k_scores<<<(N + 3) / 4, 256, 0, stream>>>(X, p, scores, N);
    k_deghist<<<(E + 255) / 256, 256, 0, stream>>>(ei, ew, deg, cnt, E);
    k_hist<<<32, HTB, 0, stream>>>(scores, hist, N);
    k_thresh<<<1, 256, 0, stream>>>(hist, Tbuf);
    k_filter<<<(N + 255) / 256, 256, 0, stream>>>(scores, Tbuf, nc, cand, N);
    k_sel<<<1, 1024, 0, stream>>>(cand, nc, p, tidx, gate);
    k_xtilde<<<(C * C) / 256, 256, 0, stream>>>(X, tidx, gate, xtl);
    k_gru<<<C / 2, 256, 0, stream>>>(xtl, W_conv, W_ih, W_hh, b_ih, b_hh, wnewT);
    k_scan1<<<NB, 256, 0, stream>>>(cnt, pref, bsum, N);
    k_scan2<<<1, 256, 0, stream>>>(bsum, NB);
    k_scan3<<<NB, 256, 0, stream>>>(pref, bsum, deg, offs, cursor, dinv, N, E);
    k_scatter<<<(E + 255) / 256, 256, 0, stream>>>(ei, ew, dinv, cursor, epack, E);
    k_xw<<<(N + 127) / 128, 256, 0, stream>>>(X, wnewT, xw, N);
    k_gather<<<(N + 1) / 2, 256, 0, stream>>>(xw, offs, epack, dinv, b_conv, out, N);
}

// Round 4
// 349.854 us; speedup vs baseline: 2.6323x; 1.2304x over previous
//
#include <hip/hip_runtime.h>
#include <hip/hip_fp16.h>
#include <math.h>

#define C 128
#define HB 2048          // histogram buckets (top 11 bits of ordered float)
#define NS 4096          // candidate capacity (pow2 for bitonic)

__device__ inline unsigned ord_f32(float f) {
    unsigned u = __float_as_uint(f);
    return u ^ ((u & 0x80000000u) ? 0xFFFFFFFFu : 0x80000000u);
}
__device__ inline float unord_f32(unsigned u) {
    return __uint_as_float(u ^ ((u & 0x80000000u) ? 0x80000000u : 0xFFFFFFFFu));
}
__device__ inline unsigned pack_h2(float a, float b) {
    __half2 h = __floats2half2_rn(a, b);
    return *(unsigned*)&h;
}

// ---------------------------------------------------------------- init: pack=0, hist=0, nc=0
__global__ void k_init(unsigned long long* __restrict__ pack, int* __restrict__ hist,
                       int* __restrict__ nc, int N) {
    int i = blockIdx.x * blockDim.x + threadIdx.x;
    if (i < N) pack[i] = 0ULL;
    if (i < HB) hist[i] = 0;
    if (i == 0) nc[0] = 0;
}

// ---------------------------------------------------------------- fused scores + histogram
__global__ __launch_bounds__(1024) void k_scorehist(const float* __restrict__ X,
                                                    const float* __restrict__ p,
                                                    float* __restrict__ scores,
                                                    int* __restrict__ hist, int N) {
    __shared__ int lh[HB];
    int t = threadIdx.x;
    for (int i = t; i < HB; i += 1024) lh[i] = 0;
    __syncthreads();
    int gw   = blockIdx.x * 16 + (t >> 6);     // 128 blocks * 16 waves = 2048 waves
    int lane = t & 63;
    for (int r = gw; r < N; r += 2048) {
        const float* xr = X + (size_t)r * C;
        float a = xr[lane] * p[lane] + xr[lane + 64] * p[lane + 64];
        #pragma unroll
        for (int o = 32; o; o >>= 1) a += __shfl_down(a, o);
        if (lane == 0) {
            scores[r] = a;
            atomicAdd(&lh[ord_f32(a) >> 21], 1);
        }
    }
    __syncthreads();
    for (int i = t; i < HB; i += 1024) {
        int v = lh[i];
        if (v) atomicAdd(&hist[i], v);
    }
}

// ---------------------------------------------------------------- degree+count: one u64 atomic per edge
__global__ void k_deghist(const int* __restrict__ ei, const float* __restrict__ ew,
                          unsigned long long* __restrict__ pack, int E) {
    int e = blockIdx.x * blockDim.x + threadIdx.x;
    if (e < E) {
        int d = ei[E + e];
        unsigned long long a = (1ULL << 40)
            | (unsigned long long)(ew[e] * 67108864.0f + 0.5f);   // fixed-point 2^26
        atomicAdd(&pack[d], a);
    }
}

// ---------------------------------------------------------------- filter with inline threshold scan
__global__ __launch_bounds__(256) void k_filter(const float* __restrict__ scores,
                                                const int* __restrict__ hist,
                                                int* __restrict__ nc,
                                                unsigned long long* __restrict__ cand, int N) {
    __shared__ int sc[256];
    __shared__ int sT;
    int t = threadIdx.x;
    int loc[8];
    int sum = 0;
    #pragma unroll
    for (int s = 0; s < 8; s++) {
        loc[s] = hist[HB - 1 - (t * 8 + s)];
        sum += loc[s];
    }
    sc[t] = sum;
    __syncthreads();
    for (int off = 1; off < 256; off <<= 1) {
        int v = (t >= off) ? sc[t - off] : 0;
        __syncthreads();
        sc[t] += v;
        __syncthreads();
    }
    int run = sc[t] - sum;
    #pragma unroll
    for (int s = 0; s < 8; s++) {
        int b = HB - 1 - (t * 8 + s);
        int nr = run + loc[s];
        if (run < C && nr >= C) sT = b;
        run = nr;
    }
    __syncthreads();
    int T = sT;
    int i = blockIdx.x * 256 + t;
    if (i < N) {
        unsigned u = ord_f32(scores[i]);
        if ((int)(u >> 21) >= T) {
            int pos = atomicAdd(nc, 1);
            if (pos < NS)
                cand[pos] = ((unsigned long long)u << 32) | (unsigned)(~(unsigned)i);
        }
    }
}

// ---------------------------------------------------------------- bitonic sort candidates desc, emit top-128
__global__ __launch_bounds__(1024) void k_sel(const unsigned long long* __restrict__ cand,
                                              const int* __restrict__ nc,
                                              const float* __restrict__ p,
                                              int* __restrict__ tidx, float* __restrict__ gate) {
    __shared__ unsigned long long sk[NS];
    __shared__ float red[16];
    __shared__ float s_pn;
    int t = threadIdx.x;
    int M = *nc; if (M > NS) M = NS;
    for (int i = t; i < NS; i += 1024) sk[i] = (i < M) ? cand[i] : 0ULL;
    float pv = 0.f;
    if (t < C) { float x = p[t]; pv = x * x; }
    #pragma unroll
    for (int o = 32; o; o >>= 1) pv += __shfl_down(pv, o);
    if ((t & 63) == 0) red[t >> 6] = pv;
    __syncthreads();
    if (t == 0) {
        float s = 0.f;
        for (int i = 0; i < 16; i++) s += red[i];
        s_pn = sqrtf(s);
    }
    for (int k = 2; k <= NS; k <<= 1) {
        for (int j = k >> 1; j > 0; j >>= 1) {
            __syncthreads();
            #pragma unroll
            for (int s = 0; s < NS / 1024; s++) {
                int idx = t + s * 1024;
                int l = idx ^ j;
                if (l > idx) {
                    unsigned long long a = sk[idx], b = sk[l];
                    bool desc = (idx & k) == 0;
                    if (desc ? (a < b) : (a > b)) { sk[idx] = b; sk[l] = a; }
                }
            }
        }
    }
    __syncthreads();
    if (t < C) {
        unsigned long long g = sk[t];
        tidx[t] = (int)(~(unsigned)(g & 0xFFFFFFFFull));
        gate[t] = tanhf(unord_f32((unsigned)(g >> 32)) / s_pn);
    }
}

// ---------------------------------------------------------------- hierarchical scan A: per-block scan + dinv
__global__ __launch_bounds__(256) void k_scan1(const unsigned long long* __restrict__ pack,
                                               int* __restrict__ pref, int* __restrict__ bsum,
                                               float* __restrict__ dinv, int N) {
    __shared__ int sc[256];
    int t = threadIdx.x;
    int i = blockIdx.x * 256 + t;
    int v = 0;
    if (i < N) {
        unsigned long long pk = pack[i];
        v = (int)(pk >> 40);
        float deg = 1.0f + (float)(pk & 0xFFFFFFFFFFULL) * (1.0f / 67108864.0f);
        dinv[i] = rsqrtf(deg);
    }
    sc[t] = v;
    __syncthreads();
    for (int off = 1; off < 256; off <<= 1) {
        int u = (t >= off) ? sc[t - off] : 0;
        __syncthreads();
        sc[t] += u;
        __syncthreads();
    }
    if (i < N) pref[i] = sc[t] - v;
    if (t == 255) bsum[blockIdx.x] = sc[255];
}

// ---------------------------------------------------------------- scan B: block sums (nb <= 256)
__global__ __launch_bounds__(256) void k_scan2(int* __restrict__ bsum, int nb) {
    __shared__ int sc[256];
    int t = threadIdx.x;
    int v = (t < nb) ? bsum[t] : 0;
    sc[t] = v;
    __syncthreads();
    for (int off = 1; off < 256; off <<= 1) {
        int u = (t >= off) ? sc[t - off] : 0;
        __syncthreads();
        sc[t] += u;
        __syncthreads();
    }
    if (t < nb) bsum[t] = sc[t] - v;
}

// ---------------------------------------------------------------- scan C: finalize offs/cursor
__global__ __launch_bounds__(256) void k_scan3(const int* __restrict__ pref, const int* __restrict__ bsum,
                                               int* __restrict__ offs, int* __restrict__ cursor,
                                               int N, int E) {
    int i = blockIdx.x * 256 + threadIdx.x;
    if (i < N) {
        int o = bsum[blockIdx.x] + pref[i];
        offs[i] = o;
        cursor[i] = o;
    }
    if (i == 0) offs[N] = E;
}

// ---------------------------------------------------------------- GRU step (X_tilde folded in) -> W_new^T
__global__ __launch_bounds__(256) void k_gru(const float* __restrict__ X,
                                             const int* __restrict__ tidx,
                                             const float* __restrict__ gate,
                                             const float* __restrict__ Wc,
                                             const float* __restrict__ W_ih, const float* __restrict__ W_hh,
                                             const float* __restrict__ b_ih, const float* __restrict__ b_hh,
                                             float* __restrict__ wnewT) {
    int t = threadIdx.x;
    int i = t & 127;
    int j = blockIdx.x * 2 + (t >> 7);
    int src = tidx[i];
    float g = gate[i];
    const float4* xr   = (const float4*)(X + (size_t)src * C);
    const float4* hr   = (const float4*)(Wc + (size_t)i * C);
    const float4* wri  = (const float4*)(W_ih + (size_t)j * C);
    const float4* wzi  = (const float4*)(W_ih + (size_t)(C + j) * C);
    const float4* wni  = (const float4*)(W_ih + (size_t)(2 * C + j) * C);
    const float4* wrh  = (const float4*)(W_hh + (size_t)j * C);
    const float4* wzh  = (const float4*)(W_hh + (size_t)(C + j) * C);
    const float4* wnh  = (const float4*)(W_hh + (size_t)(2 * C + j) * C);
    float gir = 0, giz = 0, gin = 0, ghr = 0, ghz = 0, ghn = 0;
    #pragma unroll 8
    for (int k4 = 0; k4 < C / 4; k4++) {
        float4 x = xr[k4], h = hr[k4], a;
        a = wri[k4]; gir += x.x * a.x + x.y * a.y + x.z * a.z + x.w * a.w;
        a = wzi[k4]; giz += x.x * a.x + x.y * a.y + x.z * a.z + x.w * a.w;
        a = wni[k4]; gin += x.x * a.x + x.y * a.y + x.z * a.z + x.w * a.w;
        a = wrh[k4]; ghr += h.x * a.x + h.y * a.y + h.z * a.z + h.w * a.w;
        a = wzh[k4]; ghz += h.x * a.x + h.y * a.y + h.z * a.z + h.w * a.w;
        a = wnh[k4]; ghn += h.x * a.x + h.y * a.y + h.z * a.z + h.w * a.w;
    }
    gir = g * gir + b_ih[j];         ghr += b_hh[j];
    giz = g * giz + b_ih[C + j];     ghz += b_hh[C + j];
    gin = g * gin + b_ih[2 * C + j]; ghn += b_hh[2 * C + j];
    float r = 1.f / (1.f + expf(-(gir + ghr)));
    float z = 1.f / (1.f + expf(-(giz + ghz)));
    float n = tanhf(gin + r * ghn);
    float wn = (1.f - z) * n + z * Wc[(size_t)i * C + j];
    wnewT[(size_t)j * C + i] = wn;
}

// ---------------------------------------------------------------- edge scatter into CSR order (packed 8B)
__global__ void k_scatter(const int* __restrict__ ei, const float* __restrict__ ew,
                          const float* __restrict__ dinv, int* __restrict__ cursor,
                          unsigned long long* __restrict__ epack, int E) {
    int e = blockIdx.x * blockDim.x + threadIdx.x;
    if (e < E) {
        int s = ei[e], d = ei[E + e];
        float nm = dinv[s] * ew[e] * dinv[d];
        int pos = atomicAdd(&cursor[d], 1);
        epack[pos] = ((unsigned long long)__float_as_uint(nm) << 32) | (unsigned)s;
    }
}

// ---------------------------------------------------------------- Xw = X @ W_new^T, stored fp16 (half2-packed)
__global__ __launch_bounds__(256) void k_xw(const float* __restrict__ X,
                                            const float* __restrict__ wnewT,
                                            unsigned* __restrict__ xwh, int N) {
    __shared__ float Wt[C * C];
    int t = threadIdx.x;
    for (int e = t; e < C * C; e += 256) Wt[e] = wnewT[e];
    __syncthreads();

    int r0 = blockIdx.x * 128;
    int r1 = r0 + (t & 63);
    int r2 = r1 + 64;
    int c0 = (t >> 6) * 32;
    const float4* xr1 = (const float4*)(X + (size_t)(r1 < N ? r1 : N - 1) * C);
    const float4* xr2 = (const float4*)(X + (size_t)(r2 < N ? r2 : N - 1) * C);
    float acc1[32], acc2[32];
    #pragma unroll
    for (int c = 0; c < 32; c++) { acc1[c] = 0.f; acc2[c] = 0.f; }

    for (int k4 = 0; k4 < C / 4; k4++) {
        float4 xa = xr1[k4], xb = xr2[k4];
        #pragma unroll
        for (int kk = 0; kk < 4; kk++) {
            float x1 = ((const float*)&xa)[kk];
            float x2 = ((const float*)&xb)[kk];
            const float* wrow = &Wt[(k4 * 4 + kk) * C + c0];
            #pragma unroll
            for (int cc = 0; cc < 32; cc += 4) {
                float4 wv = *(const float4*)(wrow + cc);
                acc1[cc + 0] += x1 * wv.x; acc1[cc + 1] += x1 * wv.y;
                acc1[cc + 2] += x1 * wv.z; acc1[cc + 3] += x1 * wv.w;
                acc2[cc + 0] += x2 * wv.x; acc2[cc + 1] += x2 * wv.y;
                acc2[cc + 2] += x2 * wv.z; acc2[cc + 3] += x2 * wv.w;
            }
        }
    }
    if (r1 < N) {
        unsigned* orow = xwh + (size_t)r1 * 64 + (c0 >> 1);
        #pragma unroll
        for (int cc = 0; cc < 32; cc += 8) {
            uint4 u;
            u.x = pack_h2(acc1[cc + 0], acc1[cc + 1]);
            u.y = pack_h2(acc1[cc + 2], acc1[cc + 3]);
            u.z = pack_h2(acc1[cc + 4], acc1[cc + 5]);
            u.w = pack_h2(acc1[cc + 6], acc1[cc + 7]);
            *(uint4*)(orow + (cc >> 1)) = u;
        }
    }
    if (r2 < N) {
        unsigned* orow = xwh + (size_t)r2 * 64 + (c0 >> 1);
        #pragma unroll
        for (int cc = 0; cc < 32; cc += 8) {
            uint4 u;
            u.x = pack_h2(acc2[cc + 0], acc2[cc + 1]);
            u.y = pack_h2(acc2[cc + 2], acc2[cc + 3]);
            u.z = pack_h2(acc2[cc + 4], acc2[cc + 5]);
            u.w = pack_h2(acc2[cc + 6], acc2[cc + 7]);
            *(uint4*)(orow + (cc >> 1)) = u;
        }
    }
}

// ---------------------------------------------------------------- gather: wave per node, fp16 rows
__global__ __launch_bounds__(256) void k_gather(const unsigned* __restrict__ xwh,
                                                const int* __restrict__ offs,
                                                const unsigned long long* __restrict__ epack,
                                                const float* __restrict__ dinv,
                                                const float* __restrict__ b_conv,
                                                float* __restrict__ out, int N) {
    int t = threadIdx.x;
    int v = blockIdx.x * 4 + (t >> 6);
    int lane = t & 63;
    if (v >= N) return;
    float dv = dinv[v];
    unsigned uv = xwh[(size_t)v * 64 + lane];
    __half2 hv = *(__half2*)&uv;
    float acc0 = dv * dv * __low2float(hv);
    float acc1 = dv * dv * __high2float(hv);
    int e0 = offs[v], e1 = offs[v + 1];
    int e = e0;
    for (; e + 1 < e1; e += 2) {
        unsigned long long pA = epack[e], pB = epack[e + 1];
        unsigned uA = xwh[(size_t)(unsigned)(pA & 0xFFFFFFFFull) * 64 + lane];
        unsigned uB = xwh[(size_t)(unsigned)(pB & 0xFFFFFFFFull) * 64 + lane];
        float nA = __uint_as_float((unsigned)(pA >> 32));
        float nB = __uint_as_float((unsigned)(pB >> 32));
        __half2 hA = *(__half2*)&uA;
        __half2 hB = *(__half2*)&uB;
        acc0 += nA * __low2float(hA) + nB * __low2float(hB);
        acc1 += nA * __high2float(hA) + nB * __high2float(hB);
    }
    if (e < e1) {
        unsigned long long pA = epack[e];
        unsigned uA = xwh[(size_t)(unsigned)(pA & 0xFFFFFFFFull) * 64 + lane];
        float nA = __uint_as_float((unsigned)(pA >> 32));
        __half2 hA = *(__half2*)&uA;
        acc0 += nA * __low2float(hA);
        acc1 += nA * __high2float(hA);
    }
    const float2* b2 = (const float2*)b_conv;
    float2 bb = b2[lane];
    float2* o2 = (float2*)(out + (size_t)v * C);
    o2[lane] = make_float2(acc0 + bb.x, acc1 + bb.y);
}

// ---------------------------------------------------------------- launcher
extern "C" void kernel_launch(void* const* d_in, const int* in_sizes, int n_in,
                              void* d_out, int out_size, void* d_ws, size_t ws_size,
                              hipStream_t stream) {
    const float* X      = (const float*)d_in[0];
    const float* ew     = (const float*)d_in[1];
    const float* p      = (const float*)d_in[2];
    const float* W_ih   = (const float*)d_in[3];
    const float* W_hh   = (const float*)d_in[4];
    const float* b_ih   = (const float*)d_in[5];
    const float* b_hh   = (const float*)d_in[6];
    const float* W_conv = (const float*)d_in[7];
    const float* b_conv = (const float*)d_in[8];
    const int*   ei     = (const int*)d_in[9];
    const int N = in_sizes[0] / C;
    const int E = in_sizes[1];
    float* out = (float*)d_out;
    const int NB = (N + 255) / 256;

    char* w = (char*)d_ws;
    auto alloc = [&](size_t bytes) -> void* {
        void* r = (void*)w;
        w += (bytes + 255) & ~(size_t)255;
        return r;
    };
    float* scores = (float*)alloc((size_t)N * 4);
    unsigned long long* pack = (unsigned long long*)alloc((size_t)N * 8);
    float* dinv   = (float*)alloc((size_t)N * 4);
    int*   offs   = (int*)alloc((size_t)(N + 1) * 4);
    int*   cursor = (int*)alloc((size_t)N * 4);
    int*   pref   = (int*)alloc((size_t)N * 4);
    int*   bsum   = (int*)alloc((size_t)NB * 4);
    int*   hist   = (int*)alloc(HB * 4);
    int*   nc     = (int*)alloc(256);
    unsigned long long* cand = (unsigned long long*)alloc((size_t)NS * 8);
    int*   tidx   = (int*)alloc(C * 4);
    float* gate   = (float*)alloc(C * 4);
    float* wnewT  = (float*)alloc((size_t)C * C * 4);
    unsigned long long* epack = (unsigned long long*)alloc((size_t)E * 8);
    unsigned* xwh = (unsigned*)alloc((size_t)N * 64 * 4);

    k_init<<<(N + 255) / 256, 256, 0, stream>>>(pack, hist, nc, N);
    k_scorehist<<<128, 1024, 0, stream>>>(X, p, scores, hist, N);
    k_deghist<<<(E + 255) / 256, 256, 0, stream>>>(ei, ew, pack, E);
    k_filter<<<NB, 256, 0, stream>>>(scores, hist, nc, cand, N);
    k_sel<<<1, 1024, 0, stream>>>(cand, nc, p, tidx, gate);
    k_gru<<<C / 2, 256, 0, stream>>>(X, tidx, gate, W_conv, W_ih, W_hh, b_ih, b_hh, wnewT);
    k_scan1<<<NB, 256, 0, stream>>>(pack, pref, bsum, dinv, N);
    k_scan2<<<1, 256, 0, stream>>>(bsum, NB);
    k_scan3<<<NB, 256, 0, stream>>>(pref, bsum, offs, cursor, N, E);
    k_scatter<<<(E + 255) / 256, 256, 0, stream>>>(ei, ew, dinv, cursor, epack, E);
    k_xw<<<(N + 127) / 128, 256, 0, stream>>>(X, wnewT, xwh, N);
    k_gather<<<(N + 3) / 4, 256, 0, stream>>>(xwh, offs, epack, dinv, b_conv, out, N);
}

// Round 5
// 316.538 us; speedup vs baseline: 2.9093x; 1.1053x over previous
//
#include <hip/hip_runtime.h>
#include <hip/hip_fp16.h>
#include <math.h>

#define C 128
#define HB 2048          // histogram buckets (top 11 bits of ordered float)
#define NS 4096          // candidate capacity (pow2 for bitonic)
#define SHB 128          // score/hist blocks inside k_front

__device__ inline unsigned ord_f32(float f) {
    unsigned u = __float_as_uint(f);
    return u ^ ((u & 0x80000000u) ? 0xFFFFFFFFu : 0x80000000u);
}
__device__ inline float unord_f32(unsigned u) {
    return __uint_as_float(u ^ ((u & 0x80000000u) ? 0x80000000u : 0xFFFFFFFFu));
}
__device__ inline unsigned pack_h2(float a, float b) {
    __half2 h = __floats2half2_rn(a, b);
    return *(unsigned*)&h;
}
__device__ inline unsigned long long enc_w(float w) {
    return (1ULL << 40) | (unsigned long long)(w * 67108864.0f + 0.5f);  // cnt<<40 | fixed26(w)
}

// ---------------------------------------------------------------- front: blocks [0,SHB) scores+hist, rest deg/cnt
__global__ __launch_bounds__(1024) void k_front(const float* __restrict__ X,
                                                const float* __restrict__ p,
                                                float* __restrict__ scores,
                                                int* __restrict__ hist,
                                                const int* __restrict__ ei,
                                                const float* __restrict__ ew,
                                                unsigned long long* __restrict__ pack,
                                                int N, int E) {
    int t = threadIdx.x;
    if (blockIdx.x < SHB) {
        __shared__ int lh[HB];
        for (int i = t; i < HB; i += 1024) lh[i] = 0;
        __syncthreads();
        int gw   = blockIdx.x * 16 + (t >> 6);     // SHB*16 = 2048 waves
        int lane = t & 63;
        for (int r = gw; r < N; r += 2048) {
            const float* xr = X + (size_t)r * C;
            float a = xr[lane] * p[lane] + xr[lane + 64] * p[lane + 64];
            #pragma unroll
            for (int o = 32; o; o >>= 1) a += __shfl_down(a, o);
            if (lane == 0) {
                scores[r] = a;
                atomicAdd(&lh[ord_f32(a) >> 21], 1);
            }
        }
        __syncthreads();
        for (int i = t; i < HB; i += 1024) {
            int v = lh[i];
            if (v) atomicAdd(&hist[i], v);
        }
    } else {
        int e = ((blockIdx.x - SHB) * 1024 + t) * 2;
        if (e + 1 < E) {
            int2 d2   = *(const int2*)(ei + E + e);
            float2 w2 = *(const float2*)(ew + e);
            atomicAdd(&pack[d2.x], enc_w(w2.x));
            atomicAdd(&pack[d2.y], enc_w(w2.y));
        } else if (e < E) {
            atomicAdd(&pack[ei[E + e]], enc_w(ew[e]));
        }
    }
}

// ---------------------------------------------------------------- filter with inline threshold scan
__global__ __launch_bounds__(256) void k_filter(const float* __restrict__ scores,
                                                const int* __restrict__ hist,
                                                int* __restrict__ nc,
                                                unsigned long long* __restrict__ cand, int N) {
    __shared__ int sc[256];
    __shared__ int sT;
    int t = threadIdx.x;
    int loc[8];
    int sum = 0;
    #pragma unroll
    for (int s = 0; s < 8; s++) {
        loc[s] = hist[HB - 1 - (t * 8 + s)];
        sum += loc[s];
    }
    sc[t] = sum;
    __syncthreads();
    for (int off = 1; off < 256; off <<= 1) {
        int v = (t >= off) ? sc[t - off] : 0;
        __syncthreads();
        sc[t] += v;
        __syncthreads();
    }
    int run = sc[t] - sum;
    #pragma unroll
    for (int s = 0; s < 8; s++) {
        int b = HB - 1 - (t * 8 + s);
        int nr = run + loc[s];
        if (run < C && nr >= C) sT = b;
        run = nr;
    }
    __syncthreads();
    int T = sT;
    int i = blockIdx.x * 256 + t;
    if (i < N) {
        unsigned u = ord_f32(scores[i]);
        if ((int)(u >> 21) >= T) {
            int pos = atomicAdd(nc, 1);
            if (pos < NS)
                cand[pos] = ((unsigned long long)u << 32) | (unsigned)(~(unsigned)i);
        }
    }
}

// ---------------------------------------------------------------- adaptive bitonic sort desc, emit top-128
__global__ __launch_bounds__(1024) void k_sel(const unsigned long long* __restrict__ cand,
                                              const int* __restrict__ nc,
                                              const float* __restrict__ p,
                                              int* __restrict__ tidx, float* __restrict__ gate) {
    __shared__ unsigned long long sk[NS];
    __shared__ float red[16];
    __shared__ float s_pn;
    int t = threadIdx.x;
    int M = *nc; if (M > NS) M = NS;
    int S = 256; while (S < M) S <<= 1;          // sort size: pow2 >= max(M,256)
    for (int i = t; i < S; i += 1024) sk[i] = (i < M) ? cand[i] : 0ULL;
    float pv = 0.f;
    if (t < C) { float x = p[t]; pv = x * x; }
    #pragma unroll
    for (int o = 32; o; o >>= 1) pv += __shfl_down(pv, o);
    if ((t & 63) == 0) red[t >> 6] = pv;
    __syncthreads();
    if (t == 0) {
        float s = 0.f;
        for (int i = 0; i < 16; i++) s += red[i];
        s_pn = sqrtf(s);
    }
    for (int k = 2; k <= S; k <<= 1) {
        for (int j = k >> 1; j > 0; j >>= 1) {
            __syncthreads();
            for (int idx = t; idx < S; idx += 1024) {
                int l = idx ^ j;
                if (l > idx) {
                    unsigned long long a = sk[idx], b = sk[l];
                    bool desc = (idx & k) == 0;
                    if (desc ? (a < b) : (a > b)) { sk[idx] = b; sk[l] = a; }
                }
            }
        }
    }
    __syncthreads();
    if (t < C) {
        unsigned long long g = sk[t];
        tidx[t] = (int)(~(unsigned)(g & 0xFFFFFFFFull));
        gate[t] = tanhf(unord_f32((unsigned)(g >> 32)) / s_pn);
    }
}

// ---------------------------------------------------------------- scan A: per-block scan of counts + dinv
__global__ __launch_bounds__(256) void k_scan1(const unsigned long long* __restrict__ pack,
                                               int* __restrict__ pref, int* __restrict__ bsum,
                                               float* __restrict__ dinv, int N) {
    __shared__ int sc[256];
    int t = threadIdx.x;
    int i = blockIdx.x * 256 + t;
    int v = 0;
    if (i < N) {
        unsigned long long pk = pack[i];
        v = (int)(pk >> 40);
        float deg = 1.0f + (float)(pk & 0xFFFFFFFFFFULL) * (1.0f / 67108864.0f);
        dinv[i] = rsqrtf(deg);
    }
    sc[t] = v;
    __syncthreads();
    for (int off = 1; off < 256; off <<= 1) {
        int u = (t >= off) ? sc[t - off] : 0;
        __syncthreads();
        sc[t] += u;
        __syncthreads();
    }
    if (i < N) pref[i] = sc[t] - v;
    if (t == 255) bsum[blockIdx.x] = sc[255];
}

// ---------------------------------------------------------------- scan B+C merged: each block sums its bsum prefix
__global__ __launch_bounds__(256) void k_scan3(const int* __restrict__ pref, const int* __restrict__ bsum,
                                               int* __restrict__ offs, int* __restrict__ cursor,
                                               int N, int E, int NB) {
    __shared__ int red[4];
    int t = threadIdx.x, bid = blockIdx.x;
    int v = (t < NB && t < bid) ? bsum[t] : 0;
    #pragma unroll
    for (int o = 32; o; o >>= 1) v += __shfl_down(v, o);
    if ((t & 63) == 0) red[t >> 6] = v;
    __syncthreads();
    int base = red[0] + red[1] + red[2] + red[3];
    int i = bid * 256 + t;
    if (i < N) {
        int o = base + pref[i];
        offs[i] = o;
        cursor[i] = o;
    }
    if (i == 0) offs[N] = E;
}

// ---------------------------------------------------------------- GRU step (X_tilde folded in) -> W_new^T
__global__ __launch_bounds__(256) void k_gru(const float* __restrict__ X,
                                             const int* __restrict__ tidx,
                                             const float* __restrict__ gate,
                                             const float* __restrict__ Wc,
                                             const float* __restrict__ W_ih, const float* __restrict__ W_hh,
                                             const float* __restrict__ b_ih, const float* __restrict__ b_hh,
                                             float* __restrict__ wnewT) {
    int t = threadIdx.x;
    int i = t & 127;
    int j = blockIdx.x * 2 + (t >> 7);
    int src = tidx[i];
    float g = gate[i];
    const float4* xr   = (const float4*)(X + (size_t)src * C);
    const float4* hr   = (const float4*)(Wc + (size_t)i * C);
    const float4* wri  = (const float4*)(W_ih + (size_t)j * C);
    const float4* wzi  = (const float4*)(W_ih + (size_t)(C + j) * C);
    const float4* wni  = (const float4*)(W_ih + (size_t)(2 * C + j) * C);
    const float4* wrh  = (const float4*)(W_hh + (size_t)j * C);
    const float4* wzh  = (const float4*)(W_hh + (size_t)(C + j) * C);
    const float4* wnh  = (const float4*)(W_hh + (size_t)(2 * C + j) * C);
    float gir = 0, giz = 0, gin = 0, ghr = 0, ghz = 0, ghn = 0;
    #pragma unroll 8
    for (int k4 = 0; k4 < C / 4; k4++) {
        float4 x = xr[k4], h = hr[k4], a;
        a = wri[k4]; gir += x.x * a.x + x.y * a.y + x.z * a.z + x.w * a.w;
        a = wzi[k4]; giz += x.x * a.x + x.y * a.y + x.z * a.z + x.w * a.w;
        a = wni[k4]; gin += x.x * a.x + x.y * a.y + x.z * a.z + x.w * a.w;
        a = wrh[k4]; ghr += h.x * a.x + h.y * a.y + h.z * a.z + h.w * a.w;
        a = wzh[k4]; ghz += h.x * a.x + h.y * a.y + h.z * a.z + h.w * a.w;
        a = wnh[k4]; ghn += h.x * a.x + h.y * a.y + h.z * a.z + h.w * a.w;
    }
    gir = g * gir + b_ih[j];         ghr += b_hh[j];
    giz = g * giz + b_ih[C + j];     ghz += b_hh[C + j];
    gin = g * gin + b_ih[2 * C + j]; ghn += b_hh[2 * C + j];
    float r = 1.f / (1.f + expf(-(gir + ghr)));
    float z = 1.f / (1.f + expf(-(giz + ghz)));
    float n = tanhf(gin + r * ghn);
    float wn = (1.f - z) * n + z * Wc[(size_t)i * C + j];
    wnewT[(size_t)j * C + i] = wn;
}

// ---------------------------------------------------------------- edge scatter into CSR order (2 edges/thread)
__global__ __launch_bounds__(256) void k_scatter(const int* __restrict__ ei, const float* __restrict__ ew,
                                                 const float* __restrict__ dinv, int* __restrict__ cursor,
                                                 unsigned long long* __restrict__ epack, int E) {
    int e = (blockIdx.x * 256 + threadIdx.x) * 2;
    if (e + 1 < E) {
        int2 s2   = *(const int2*)(ei + e);
        int2 d2   = *(const int2*)(ei + E + e);
        float2 w2 = *(const float2*)(ew + e);
        float nm0 = dinv[s2.x] * w2.x * dinv[d2.x];
        float nm1 = dinv[s2.y] * w2.y * dinv[d2.y];
        int p0 = atomicAdd(&cursor[d2.x], 1);
        int p1 = atomicAdd(&cursor[d2.y], 1);
        epack[p0] = ((unsigned long long)__float_as_uint(nm0) << 32) | (unsigned)s2.x;
        epack[p1] = ((unsigned long long)__float_as_uint(nm1) << 32) | (unsigned)s2.y;
    } else if (e < E) {
        int s = ei[e], d = ei[E + e];
        float nm = dinv[s] * ew[e] * dinv[d];
        int pos = atomicAdd(&cursor[d], 1);
        epack[pos] = ((unsigned long long)__float_as_uint(nm) << 32) | (unsigned)s;
    }
}

// ---------------------------------------------------------------- Xw = X @ W_new^T, stored fp16 (half2-packed)
__global__ __launch_bounds__(256) void k_xw(const float* __restrict__ X,
                                            const float* __restrict__ wnewT,
                                            unsigned* __restrict__ xwh, int N) {
    __shared__ float Wt[C * C];
    int t = threadIdx.x;
    for (int e = t; e < C * C; e += 256) Wt[e] = wnewT[e];
    __syncthreads();

    int r0 = blockIdx.x * 128;
    int r1 = r0 + (t & 63);
    int r2 = r1 + 64;
    int c0 = (t >> 6) * 32;
    const float4* xr1 = (const float4*)(X + (size_t)(r1 < N ? r1 : N - 1) * C);
    const float4* xr2 = (const float4*)(X + (size_t)(r2 < N ? r2 : N - 1) * C);
    float acc1[32], acc2[32];
    #pragma unroll
    for (int c = 0; c < 32; c++) { acc1[c] = 0.f; acc2[c] = 0.f; }

    for (int k4 = 0; k4 < C / 4; k4++) {
        float4 xa = xr1[k4], xb = xr2[k4];
        #pragma unroll
        for (int kk = 0; kk < 4; kk++) {
            float x1 = ((const float*)&xa)[kk];
            float x2 = ((const float*)&xb)[kk];
            const float* wrow = &Wt[(k4 * 4 + kk) * C + c0];
            #pragma unroll
            for (int cc = 0; cc < 32; cc += 4) {
                float4 wv = *(const float4*)(wrow + cc);
                acc1[cc + 0] += x1 * wv.x; acc1[cc + 1] += x1 * wv.y;
                acc1[cc + 2] += x1 * wv.z; acc1[cc + 3] += x1 * wv.w;
                acc2[cc + 0] += x2 * wv.x; acc2[cc + 1] += x2 * wv.y;
                acc2[cc + 2] += x2 * wv.z; acc2[cc + 3] += x2 * wv.w;
            }
        }
    }
    if (r1 < N) {
        unsigned* orow = xwh + (size_t)r1 * 64 + (c0 >> 1);
        #pragma unroll
        for (int cc = 0; cc < 32; cc += 8) {
            uint4 u;
            u.x = pack_h2(acc1[cc + 0], acc1[cc + 1]);
            u.y = pack_h2(acc1[cc + 2], acc1[cc + 3]);
            u.z = pack_h2(acc1[cc + 4], acc1[cc + 5]);
            u.w = pack_h2(acc1[cc + 6], acc1[cc + 7]);
            *(uint4*)(orow + (cc >> 1)) = u;
        }
    }
    if (r2 < N) {
        unsigned* orow = xwh + (size_t)r2 * 64 + (c0 >> 1);
        #pragma unroll
        for (int cc = 0; cc < 32; cc += 8) {
            uint4 u;
            u.x = pack_h2(acc2[cc + 0], acc2[cc + 1]);
            u.y = pack_h2(acc2[cc + 2], acc2[cc + 3]);
            u.z = pack_h2(acc2[cc + 4], acc2[cc + 5]);
            u.w = pack_h2(acc2[cc + 6], acc2[cc + 7]);
            *(uint4*)(orow + (cc >> 1)) = u;
        }
    }
}

// ---------------------------------------------------------------- gather: wave per node, 4-wide unroll, nt stores
__global__ __launch_bounds__(256) void k_gather(const unsigned* __restrict__ xwh,
                                                const int* __restrict__ offs,
                                                const unsigned long long* __restrict__ epack,
                                                const float* __restrict__ dinv,
                                                const float* __restrict__ b_conv,
                                                float* __restrict__ out, int N) {
    int t = threadIdx.x;
    int v = blockIdx.x * 4 + (t >> 6);
    int lane = t & 63;
    if (v >= N) return;
    float dv = dinv[v];
    unsigned uv = xwh[(size_t)v * 64 + lane];
    __half2 hv = *(__half2*)&uv;
    float acc0 = dv * dv * __low2float(hv);
    float acc1 = dv * dv * __high2float(hv);
    int e0 = offs[v], e1 = offs[v + 1];
    int e = e0;
    for (; e + 3 < e1; e += 4) {
        unsigned long long p0 = __builtin_nontemporal_load(&epack[e + 0]);
        unsigned long long p1 = __builtin_nontemporal_load(&epack[e + 1]);
        unsigned long long p2 = __builtin_nontemporal_load(&epack[e + 2]);
        unsigned long long p3 = __builtin_nontemporal_load(&epack[e + 3]);
        unsigned u0 = xwh[(size_t)(unsigned)(p0 & 0xFFFFFFFFull) * 64 + lane];
        unsigned u1 = xwh[(size_t)(unsigned)(p1 & 0xFFFFFFFFull) * 64 + lane];
        unsigned u2 = xwh[(size_t)(unsigned)(p2 & 0xFFFFFFFFull) * 64 + lane];
        unsigned u3 = xwh[(size_t)(unsigned)(p3 & 0xFFFFFFFFull) * 64 + lane];
        float n0 = __uint_as_float((unsigned)(p0 >> 32));
        float n1 = __uint_as_float((unsigned)(p1 >> 32));
        float n2 = __uint_as_float((unsigned)(p2 >> 32));
        float n3 = __uint_as_float((unsigned)(p3 >> 32));
        __half2 h0 = *(__half2*)&u0, h1 = *(__half2*)&u1;
        __half2 h2 = *(__half2*)&u2, h3 = *(__half2*)&u3;
        acc0 += n0 * __low2float(h0) + n1 * __low2float(h1)
              + n2 * __low2float(h2) + n3 * __low2float(h3);
        acc1 += n0 * __high2float(h0) + n1 * __high2float(h1)
              + n2 * __high2float(h2) + n3 * __high2float(h3);
    }
    for (; e < e1; e++) {
        unsigned long long pA = __builtin_nontemporal_load(&epack[e]);
        unsigned uA = xwh[(size_t)(unsigned)(pA & 0xFFFFFFFFull) * 64 + lane];
        float nA = __uint_as_float((unsigned)(pA >> 32));
        __half2 hA = *(__half2*)&uA;
        acc0 += nA * __low2float(hA);
        acc1 += nA * __high2float(hA);
    }
    const float2* b2 = (const float2*)b_conv;
    float2 bb = b2[lane];
    unsigned long long ov = ((unsigned long long)__float_as_uint(acc1 + bb.y) << 32)
                          |  (unsigned long long)__float_as_uint(acc0 + bb.x);
    __builtin_nontemporal_store(ov, (unsigned long long*)(out + (size_t)v * C) + lane);
}

// ---------------------------------------------------------------- launcher
extern "C" void kernel_launch(void* const* d_in, const int* in_sizes, int n_in,
                              void* d_out, int out_size, void* d_ws, size_t ws_size,
                              hipStream_t stream) {
    const float* X      = (const float*)d_in[0];
    const float* ew     = (const float*)d_in[1];
    const float* p      = (const float*)d_in[2];
    const float* W_ih   = (const float*)d_in[3];
    const float* W_hh   = (const float*)d_in[4];
    const float* b_ih   = (const float*)d_in[5];
    const float* b_hh   = (const float*)d_in[6];
    const float* W_conv = (const float*)d_in[7];
    const float* b_conv = (const float*)d_in[8];
    const int*   ei     = (const int*)d_in[9];
    const int N = in_sizes[0] / C;
    const int E = in_sizes[1];
    float* out = (float*)d_out;
    const int NB = (N + 255) / 256;

    char* w = (char*)d_ws;
    auto alloc = [&](size_t bytes) -> void* {
        void* r = (void*)w;
        w += (bytes + 255) & ~(size_t)255;
        return r;
    };
    // zero-init region: pack + hist + nc (single memset)
    unsigned long long* pack = (unsigned long long*)alloc((size_t)N * 8);
    int*   hist   = (int*)alloc(HB * 4);
    int*   nc     = (int*)alloc(256);
    size_t zbytes = (size_t)(w - (char*)d_ws);
    float* scores = (float*)alloc((size_t)N * 4);
    float* dinv   = (float*)alloc((size_t)N * 4);
    int*   offs   = (int*)alloc((size_t)(N + 1) * 4);
    int*   cursor = (int*)alloc((size_t)N * 4);
    int*   pref   = (int*)alloc((size_t)N * 4);
    int*   bsum   = (int*)alloc((size_t)NB * 4);
    unsigned long long* cand = (unsigned long long*)alloc((size_t)NS * 8);
    int*   tidx   = (int*)alloc(C * 4);
    float* gate   = (float*)alloc(C * 4);
    float* wnewT  = (float*)alloc((size_t)C * C * 4);
    unsigned long long* epack = (unsigned long long*)alloc((size_t)E * 8);
    unsigned* xwh = (unsigned*)alloc((size_t)N * 64 * 4);

    hipMemsetAsync(d_ws, 0, zbytes, stream);
    int edgeBlocks = (E / 2 + 1023) / 1024;
    k_front<<<SHB + edgeBlocks, 1024, 0, stream>>>(X, p, scores, hist, ei, ew, pack, N, E);
    k_filter<<<NB, 256, 0, stream>>>(scores, hist, nc, cand, N);
    k_sel<<<1, 1024, 0, stream>>>(cand, nc, p, tidx, gate);
    k_gru<<<C / 2, 256, 0, stream>>>(X, tidx, gate, W_conv, W_ih, W_hh, b_ih, b_hh, wnewT);
    k_scan1<<<NB, 256, 0, stream>>>(pack, pref, bsum, dinv, N);
    k_scan3<<<NB, 256, 0, stream>>>(pref, bsum, offs, cursor, N, E, NB);
    k_scatter<<<(E / 2 + 255) / 256, 256, 0, stream>>>(ei, ew, dinv, cursor, epack, E);
    k_xw<<<(N + 127) / 128, 256, 0, stream>>>(X, wnewT, xwh, N);
    k_gather<<<(N + 3) / 4, 256, 0, stream>>>(xwh, offs, epack, dinv, b_conv, out, N);
}